// Round 4
// baseline (367.215 us; speedup 1.0000x reference)
//
#include <hip/hip_runtime.h>
#include <hip/hip_bf16.h>

#define NN 512
#define NFG 128
#define NFR 64
#define BT 256

typedef __attribute__((ext_vector_type(8))) short bfrag;   // 8 bf16
typedef __attribute__((ext_vector_type(4))) float f32x4;

__device__ __forceinline__ short f2bf(float f) {
    unsigned u = __float_as_uint(f);
    return (short)((u + 0x7fffu + ((u >> 16) & 1u)) >> 16);
}

// ---------------------------------------------------------------------------
// K1: theta = X@thw^T + thb ; phi = X@phw^T + phb   (bf16 MFMA)
// thetaS/phiS: [BT*512][64] bf16 shorts, stored in the f32 "out" region
// (scratch until K3 overwrites it with the final out).
__global__ __launch_bounds__(256) void k_proj(const float* __restrict__ X,
                                              const float* __restrict__ thw,
                                              const float* __restrict__ thb,
                                              const float* __restrict__ phw,
                                              const float* __restrict__ phb,
                                              short* __restrict__ thetaS,
                                              short* __restrict__ phiS) {
    __shared__ short Xs[64][136];      // 17,408 B
    __shared__ short wS[2][64][136];   // 34,816 B  (theta_w, phi_w as bf16)
    __shared__ float bS[2][64];        //     512 B
    const int bt = blockIdx.y, n0 = blockIdx.x * 64, tid = threadIdx.x;

    {   // stage X tile (cast f32 -> bf16), coalesced float4 reads
        int row = tid >> 2, seg = tid & 3;
        const float* src = X + ((size_t)(bt * NN + n0 + row)) * NFG + seg * 32;
        short tmp[32];
        #pragma unroll
        for (int k = 0; k < 8; ++k) {
            float4 v = reinterpret_cast<const float4*>(src)[k];
            tmp[k*4+0] = f2bf(v.x); tmp[k*4+1] = f2bf(v.y);
            tmp[k*4+2] = f2bf(v.z); tmp[k*4+3] = f2bf(v.w);
        }
        #pragma unroll
        for (int k = 0; k < 4; ++k)
            reinterpret_cast<uint4*>(&Xs[row][seg * 32])[k] =
                reinterpret_cast<uint4*>(tmp)[k];
    }
    #pragma unroll
    for (int k = 0; k < 32; ++k) {     // stage both weight matrices as bf16
        int idx = k * 256 + tid;       // 8192 = 64*128
        int r = idx >> 7, f = idx & 127;
        wS[0][r][f] = f2bf(thw[idx]);
        wS[1][r][f] = f2bf(phw[idx]);
    }
    if (tid < 64) { bS[0][tid] = thb[tid]; bS[1][tid] = phb[tid]; }
    __syncthreads();

    const int wid = tid >> 6, lane = tid & 63;
    const int l16 = lane & 15, lg = lane >> 4;

    bfrag xa[4];
    #pragma unroll
    for (int kk = 0; kk < 4; ++kk)
        xa[kk] = *reinterpret_cast<const bfrag*>(&Xs[wid * 16 + l16][kk * 32 + lg * 8]);

    for (int pass = 0; pass < 2; ++pass) {
        short* dst = pass ? phiS : thetaS;
        #pragma unroll
        for (int c = 0; c < 4; ++c) {
            f32x4 acc = {0.f, 0.f, 0.f, 0.f};
            #pragma unroll
            for (int kk = 0; kk < 4; ++kk) {
                bfrag b = *reinterpret_cast<const bfrag*>(
                    &wS[pass][c * 16 + l16][kk * 32 + lg * 8]);
                acc = __builtin_amdgcn_mfma_f32_16x16x32_bf16(xa[kk], b, acc, 0, 0, 0);
            }
            float bv = bS[pass][c * 16 + l16];
            #pragma unroll
            for (int r = 0; r < 4; ++r) {
                int n = n0 + wid * 16 + lg * 4 + r;
                dst[((size_t)(bt * NN + n)) * NFR + c * 16 + l16] = f2bf(acc[r] + bv);
            }
        }
    }
}

// ---------------------------------------------------------------------------
// K2: sim = theta.phi^T/8 with exact distance mask -> softmax -> P (f32, rg)
__global__ __launch_bounds__(512) void k_sim(const short* __restrict__ thetaS,
                                             const short* __restrict__ phiS,
                                             const float* __restrict__ boxes,
                                             float* __restrict__ rgG) {
    __shared__ float S[64][516];       // 132,096 B
    __shared__ float cxs[NN], cys[NN]; //   4,096 B
    const int bt = blockIdx.y, n0 = blockIdx.x * 64, tid = threadIdx.x;
    const int wid = tid >> 6, lane = tid & 63;
    const int l16 = lane & 15, lg = lane >> 4;
    const int rsub = wid & 3, ch = wid >> 2;

    {   // centers: bit-exact vs numpy ((x1+x2)*0.5 in f32 RNE)
        float4 b = reinterpret_cast<const float4*>(boxes)[bt * NN + tid];
        cxs[tid] = __fmul_rn(__fadd_rn(b.x, b.z), 0.5f);
        cys[tid] = __fmul_rn(__fadd_rn(b.y, b.w), 0.5f);
    }

    bfrag thA[2];
    #pragma unroll
    for (int kk = 0; kk < 2; ++kk)
        thA[kk] = *reinterpret_cast<const bfrag*>(
            &thetaS[((size_t)(bt * NN + n0 + rsub * 16 + l16)) * NFR + kk * 32 + lg * 8]);
    __syncthreads();

    // -------- sim + exact mask into S -----------------------------------
    #pragma unroll 1
    for (int mt = 0; mt < 8; ++mt) {
        int m0 = mt * 64;
        #pragma unroll
        for (int ci = 0; ci < 2; ++ci) {
            int cs = ch * 2 + ci;
            int m = m0 + cs * 16 + l16;
            f32x4 acc = {0.f, 0.f, 0.f, 0.f};
            #pragma unroll
            for (int kk = 0; kk < 2; ++kk) {
                bfrag pb = *reinterpret_cast<const bfrag*>(
                    &phiS[((size_t)(bt * NN + m)) * NFR + kk * 32 + lg * 8]);
                acc = __builtin_amdgcn_mfma_f32_16x16x32_bf16(thA[kk], pb, acc, 0, 0, 0);
            }
            float cxm = cxs[m], cym = cys[m];
            #pragma unroll
            for (int r = 0; r < 4; ++r) {
                int nl = rsub * 16 + lg * 4 + r;
                // masked  <=>  sqrt_RNE(d2) > 16.0f  <=>  d2 > 256+2^-15
                float dx = __fsub_rn(cxs[n0 + nl], cxm);
                float dy = __fsub_rn(cys[n0 + nl], cym);
                float d2 = __fadd_rn(__fmul_rn(dx, dx), __fmul_rn(dy, dy));
                S[nl][m] = (d2 > __uint_as_float(0x43800001u))
                               ? -__builtin_inff() : acc[r] * 0.125f;
            }
        }
    }
    __syncthreads();

    // -------- softmax per row (8 threads/row) + write rg (f32) ----------
    {
        int row = tid >> 3, j = tid & 7;
        float* Sp = &S[row][j * 64];
        float mx = -__builtin_inff();
        #pragma unroll
        for (int k = 0; k < 16; ++k) {
            float4 v = *reinterpret_cast<float4*>(Sp + k * 4);
            mx = fmaxf(mx, fmaxf(fmaxf(v.x, v.y), fmaxf(v.z, v.w)));
        }
        mx = fmaxf(mx, __shfl_xor(mx, 1));
        mx = fmaxf(mx, __shfl_xor(mx, 2));
        mx = fmaxf(mx, __shfl_xor(mx, 4));
        float sm = 0.f;
        #pragma unroll
        for (int k = 0; k < 16; ++k) {
            float4 v = *reinterpret_cast<float4*>(Sp + k * 4);
            v.x = __expf(v.x - mx); v.y = __expf(v.y - mx);
            v.z = __expf(v.z - mx); v.w = __expf(v.w - mx);
            sm += (v.x + v.y) + (v.z + v.w);
            *reinterpret_cast<float4*>(Sp + k * 4) = v;
        }
        sm += __shfl_xor(sm, 1);
        sm += __shfl_xor(sm, 2);
        sm += __shfl_xor(sm, 4);
        float inv = 1.0f / sm;
        float* rp = rgG + ((size_t)(bt * NN) + n0 + row) * NN + j * 64;
        #pragma unroll
        for (int k = 0; k < 16; ++k) {
            float4 a = *reinterpret_cast<float4*>(Sp + k * 4);
            a.x *= inv; a.y *= inv; a.z *= inv; a.w *= inv;
            *reinterpret_cast<float4*>(rp + k * 4) = a;
        }
    }
}

// ---------------------------------------------------------------------------
// K3: out = (P @ X) @ W   (reads f32 P from rg; two MFMA stages; f32 out)
__global__ __launch_bounds__(256) void k_pool(const float* __restrict__ rgG,
                                              const float* __restrict__ X,
                                              const float* __restrict__ W,
                                              float* __restrict__ outG) {
    __shared__ short Xt[128][72];      // 18,432 B  X^T tile [f][m]
    __shared__ short poolS[64][136];   // 17,408 B  pool [n][f] bf16
    __shared__ short WtS[128][136];    // 34,816 B  W^T [g][f] bf16
    const int bt = blockIdx.y, n0 = blockIdx.x * 64, tid = threadIdx.x;
    const int wid = tid >> 6, lane = tid & 63;
    const int l16 = lane & 15, lg = lane >> 4;

    #pragma unroll
    for (int k = 0; k < 64; ++k) {     // stage W^T bf16 (16384 elems)
        int idx = k * 256 + tid;
        int f = idx >> 7, g = idx & 127;
        WtS[g][f] = f2bf(W[idx]);
    }

    f32x4 acc[8];
    #pragma unroll
    for (int ft = 0; ft < 8; ++ft) acc[ft] = f32x4{0.f, 0.f, 0.f, 0.f};

    // -------- stage 1: pool = P @ X  ------------------------------------
    #pragma unroll 1
    for (int mt = 0; mt < 8; ++mt) {
        __syncthreads();
        {   // stage X^T tile [128 f][64 m]
            int m = tid >> 2, seg = tid & 3;
            const float* src = X + ((size_t)(bt * NN + mt * 64 + m)) * NFG + seg * 32;
            #pragma unroll
            for (int k = 0; k < 8; ++k) {
                float4 v = reinterpret_cast<const float4*>(src)[k];
                int f = seg * 32 + k * 4;
                Xt[f + 0][m] = f2bf(v.x); Xt[f + 1][m] = f2bf(v.y);
                Xt[f + 2][m] = f2bf(v.z); Xt[f + 3][m] = f2bf(v.w);
            }
        }
        // P fragment: load 16 f32, convert to two bf16 fragments
        bfrag pa[2];
        const float* prow = rgG + ((size_t)(bt * NN + n0 + wid * 16 + l16)) * NN + mt * 64;
        #pragma unroll
        for (int kk = 0; kk < 2; ++kk) {
            float4 a = *reinterpret_cast<const float4*>(prow + kk * 32 + lg * 8);
            float4 b = *reinterpret_cast<const float4*>(prow + kk * 32 + lg * 8 + 4);
            short t[8] = { f2bf(a.x), f2bf(a.y), f2bf(a.z), f2bf(a.w),
                           f2bf(b.x), f2bf(b.y), f2bf(b.z), f2bf(b.w) };
            pa[kk] = *reinterpret_cast<bfrag*>(t);
        }
        __syncthreads();
        #pragma unroll
        for (int ft = 0; ft < 8; ++ft) {
            #pragma unroll
            for (int kk = 0; kk < 2; ++kk) {
                bfrag b = *reinterpret_cast<const bfrag*>(
                    &Xt[ft * 16 + l16][kk * 32 + lg * 8]);
                acc[ft] = __builtin_amdgcn_mfma_f32_16x16x32_bf16(pa[kk], b, acc[ft], 0, 0, 0);
            }
        }
    }
    __syncthreads();
    #pragma unroll
    for (int ft = 0; ft < 8; ++ft)
        #pragma unroll
        for (int r = 0; r < 4; ++r)
            poolS[wid * 16 + lg * 4 + r][ft * 16 + l16] = f2bf(acc[ft][r]);
    __syncthreads();

    // -------- stage 2: out = pool @ W  (f32 stores) ----------------------
    bfrag a2[4];
    #pragma unroll
    for (int kk = 0; kk < 4; ++kk)
        a2[kk] = *reinterpret_cast<const bfrag*>(&poolS[wid * 16 + l16][kk * 32 + lg * 8]);
    #pragma unroll
    for (int gt = 0; gt < 8; ++gt) {
        f32x4 o = {0.f, 0.f, 0.f, 0.f};
        #pragma unroll
        for (int kk = 0; kk < 4; ++kk) {
            bfrag b2 = *reinterpret_cast<const bfrag*>(&WtS[gt * 16 + l16][kk * 32 + lg * 8]);
            o = __builtin_amdgcn_mfma_f32_16x16x32_bf16(a2[kk], b2, o, 0, 0, 0);
        }
        #pragma unroll
        for (int r = 0; r < 4; ++r) {
            int n = n0 + wid * 16 + lg * 4 + r;
            outG[((size_t)(bt * NN + n)) * NFG + gt * 16 + l16] = o[r];
        }
    }
}

// ---------------------------------------------------------------------------
extern "C" void kernel_launch(void* const* d_in, const int* in_sizes, int n_in,
                              void* d_out, int out_size, void* d_ws, size_t ws_size,
                              hipStream_t stream) {
    const float* X     = (const float*)d_in[0];
    const float* boxes = (const float*)d_in[1];
    const float* W     = (const float*)d_in[2];
    const float* thw   = (const float*)d_in[3];
    const float* thb   = (const float*)d_in[4];
    const float* phw   = (const float*)d_in[5];
    const float* phb   = (const float*)d_in[6];

    // Outputs are FLOAT32: out [256*512][128] f32, then rg [256*512][512] f32.
    // Zero workspace use: theta||phi (bf16 shorts, 33.5 MB) live inside the
    // 67 MB f32 out region until K3 overwrites it with the final out.
    float* outR   = (float*)d_out;
    float* rgR    = outR + (size_t)BT * NN * NFG;
    short* thetaS = (short*)d_out;                       // 8,388,608 shorts
    short* phiS   = thetaS + (size_t)BT * NN * NFR;      // 8,388,608 shorts

    k_proj<<<dim3(8, BT), 256, 0, stream>>>(X, thw, thb, phw, phb, thetaS, phiS);
    k_sim <<<dim3(8, BT), 512, 0, stream>>>(thetaS, phiS, boxes, rgR);
    k_pool<<<dim3(8, BT), 256, 0, stream>>>(rgR, X, W, outR);
}

// Round 5
// 291.978 us; speedup vs baseline: 1.2577x; 1.2577x over previous
//
#include <hip/hip_runtime.h>
#include <hip/hip_bf16.h>

#define NN 512
#define NFG 128
#define NFR 64
#define BT 256

typedef __attribute__((ext_vector_type(8))) short bfrag;   // 8 bf16
typedef __attribute__((ext_vector_type(4))) float f32x4;

__device__ __forceinline__ short f2bf(float f) {
    unsigned u = __float_as_uint(f);
    return (short)((u + 0x7fffu + ((u >> 16) & 1u)) >> 16);
}

// ---------------------------------------------------------------------------
// k_prep: WtB[g][f] = bf16(W[f][g])   (fused path only)
__global__ __launch_bounds__(256) void k_prep(const float* __restrict__ W,
                                              short* __restrict__ WtB) {
    int i = blockIdx.x * 256 + threadIdx.x;
    if (i < NFG * NFG) { int f = i >> 7, g = i & 127; WtB[g * NFG + f] = f2bf(W[i]); }
}

// ---------------------------------------------------------------------------
// k_proj: theta = X@thw^T + thb ; phi = X@phw^T + phb   (bf16 MFMA)
__global__ __launch_bounds__(256) void k_proj(const float* __restrict__ X,
                                              const float* __restrict__ thw,
                                              const float* __restrict__ thb,
                                              const float* __restrict__ phw,
                                              const float* __restrict__ phb,
                                              short* __restrict__ thetaS,
                                              short* __restrict__ phiS) {
    __shared__ short Xs[64][136];
    __shared__ short wS[2][64][136];
    __shared__ float bS[2][64];
    const int bt = blockIdx.y, n0 = blockIdx.x * 64, tid = threadIdx.x;

    {
        int row = tid >> 2, seg = tid & 3;
        const float* src = X + ((size_t)(bt * NN + n0 + row)) * NFG + seg * 32;
        short tmp[32];
        #pragma unroll
        for (int k = 0; k < 8; ++k) {
            float4 v = reinterpret_cast<const float4*>(src)[k];
            tmp[k*4+0] = f2bf(v.x); tmp[k*4+1] = f2bf(v.y);
            tmp[k*4+2] = f2bf(v.z); tmp[k*4+3] = f2bf(v.w);
        }
        #pragma unroll
        for (int k = 0; k < 4; ++k)
            reinterpret_cast<uint4*>(&Xs[row][seg * 32])[k] =
                reinterpret_cast<uint4*>(tmp)[k];
    }
    #pragma unroll
    for (int k = 0; k < 32; ++k) {
        int idx = k * 256 + tid;
        int r = idx >> 7, f = idx & 127;
        wS[0][r][f] = f2bf(thw[idx]);
        wS[1][r][f] = f2bf(phw[idx]);
    }
    if (tid < 64) { bS[0][tid] = thb[tid]; bS[1][tid] = phb[tid]; }
    __syncthreads();

    const int wid = tid >> 6, lane = tid & 63;
    const int l16 = lane & 15, lg = lane >> 4;

    bfrag xa[4];
    #pragma unroll
    for (int kk = 0; kk < 4; ++kk)
        xa[kk] = *reinterpret_cast<const bfrag*>(&Xs[wid * 16 + l16][kk * 32 + lg * 8]);

    for (int pass = 0; pass < 2; ++pass) {
        short* dst = pass ? phiS : thetaS;
        #pragma unroll
        for (int c = 0; c < 4; ++c) {
            f32x4 acc = {0.f, 0.f, 0.f, 0.f};
            #pragma unroll
            for (int kk = 0; kk < 4; ++kk) {
                bfrag b = *reinterpret_cast<const bfrag*>(
                    &wS[pass][c * 16 + l16][kk * 32 + lg * 8]);
                acc = __builtin_amdgcn_mfma_f32_16x16x32_bf16(xa[kk], b, acc, 0, 0, 0);
            }
            float bv = bS[pass][c * 16 + l16];
            #pragma unroll
            for (int r = 0; r < 4; ++r) {
                int n = n0 + wid * 16 + lg * 4 + r;
                dst[((size_t)(bt * NN + n)) * NFR + c * 16 + l16] = f2bf(acc[r] + bv);
            }
        }
    }
}

// ---------------------------------------------------------------------------
// k_fused: per (frame, 32-row block):
//   QK^T (exact mask) -> softmax (strided, conflict-free) -> rg write
//   -> pool = P@X (X tiles staged 32 rows at a time) -> out = pool@W
__global__ __launch_bounds__(256) void k_fused(const short* __restrict__ thetaS,
                                               const short* __restrict__ phiS,
                                               const short* __restrict__ WtB,
                                               const float* __restrict__ X,
                                               const float* __restrict__ boxes,
                                               float* __restrict__ outG,
                                               float* __restrict__ rgG) {
    __shared__ float S[32][516];          // 66,048 B
    __shared__ float cxs[NN], cys[NN];    //  4,096 B
    __shared__ float invS[32];            //    128 B
    __shared__ short XsBuf[32 * 140];     //  8,960 B (PV X tile; reused as poolS)
    // total 79,232 B -> 2 blocks/CU

    // XCD-aware decomposition: 16 blocks of one frame land on one XCD
    const int bid = blockIdx.x;                    // 0..4095
    const int jj = bid >> 3;
    const int bt = (bid & 7) * 32 + (jj >> 4);
    const int n0 = (jj & 15) * 32;
    const int tid = threadIdx.x;
    const int wid = tid >> 6, lane = tid & 63;
    const int l16 = lane & 15, lg = lane >> 4;
    const int nsub = wid & 1;        // row subtile (16 rows)
    const int mhalf = wid >> 1;      // m half (QK) / f quad (PV) / g quad (W)

    {   // centers: bit-exact vs numpy f32 RNE
        float4 b0 = reinterpret_cast<const float4*>(boxes)[bt * NN + tid];
        float4 b1 = reinterpret_cast<const float4*>(boxes)[bt * NN + 256 + tid];
        cxs[tid]       = __fmul_rn(__fadd_rn(b0.x, b0.z), 0.5f);
        cys[tid]       = __fmul_rn(__fadd_rn(b0.y, b0.w), 0.5f);
        cxs[256 + tid] = __fmul_rn(__fadd_rn(b1.x, b1.z), 0.5f);
        cys[256 + tid] = __fmul_rn(__fadd_rn(b1.y, b1.w), 0.5f);
    }

    bfrag thA[2];
    #pragma unroll
    for (int kk = 0; kk < 2; ++kk)
        thA[kk] = *reinterpret_cast<const bfrag*>(
            &thetaS[((size_t)(bt * NN + n0 + nsub * 16 + l16)) * NFR + kk * 32 + lg * 8]);
    __syncthreads();

    // -------- QK: sim + exact mask into S --------------------------------
    #pragma unroll 4
    for (int mi = 0; mi < 16; ++mi) {
        int m = (mhalf * 16 + mi) * 16 + l16;
        f32x4 acc = {0.f, 0.f, 0.f, 0.f};
        #pragma unroll
        for (int kk = 0; kk < 2; ++kk) {
            bfrag pb = *reinterpret_cast<const bfrag*>(
                &phiS[((size_t)(bt * NN + m)) * NFR + kk * 32 + lg * 8]);
            acc = __builtin_amdgcn_mfma_f32_16x16x32_bf16(thA[kk], pb, acc, 0, 0, 0);
        }
        float cxm = cxs[m], cym = cys[m];
        #pragma unroll
        for (int r = 0; r < 4; ++r) {
            int nl = nsub * 16 + lg * 4 + r;
            // masked <=> sqrt_RNE(d2) > 16.0f <=> d2 > 256+2^-15
            float dx = __fsub_rn(cxs[n0 + nl], cxm);
            float dy = __fsub_rn(cys[n0 + nl], cym);
            float d2 = __fadd_rn(__fmul_rn(dx, dx), __fmul_rn(dy, dy));
            S[nl][m] = (d2 > __uint_as_float(0x43800001u))
                           ? -__builtin_inff() : acc[r] * 0.125f;
        }
    }
    __syncthreads();

    // -------- softmax per row: 8 threads/row, 32-col stride (2-way max) --
    {
        int row = tid >> 3, j = tid & 7;
        float mx = -__builtin_inff();
        #pragma unroll
        for (int k = 0; k < 16; ++k) {
            float4 v = *reinterpret_cast<float4*>(&S[row][j * 4 + 32 * k]);
            mx = fmaxf(mx, fmaxf(fmaxf(v.x, v.y), fmaxf(v.z, v.w)));
        }
        mx = fmaxf(mx, __shfl_xor(mx, 1));
        mx = fmaxf(mx, __shfl_xor(mx, 2));
        mx = fmaxf(mx, __shfl_xor(mx, 4));
        float sm = 0.f;
        #pragma unroll
        for (int k = 0; k < 16; ++k) {
            float4 v = *reinterpret_cast<float4*>(&S[row][j * 4 + 32 * k]);
            v.x = __expf(v.x - mx); v.y = __expf(v.y - mx);
            v.z = __expf(v.z - mx); v.w = __expf(v.w - mx);
            sm += (v.x + v.y) + (v.z + v.w);
            *reinterpret_cast<float4*>(&S[row][j * 4 + 32 * k]) = v;   // exp, unnormalized
        }
        sm += __shfl_xor(sm, 1);
        sm += __shfl_xor(sm, 2);
        sm += __shfl_xor(sm, 4);
        float inv = 1.0f / sm;
        if (j == 0) invS[row] = inv;
        float* rp = rgG + ((size_t)(bt * NN) + n0 + row) * NN;
        #pragma unroll
        for (int k = 0; k < 16; ++k) {
            float4 a = *reinterpret_cast<float4*>(&S[row][j * 4 + 32 * k]);
            a.x *= inv; a.y *= inv; a.z *= inv; a.w *= inv;
            *reinterpret_cast<float4*>(rp + j * 4 + 32 * k) = a;
        }
    }
    __syncthreads();

    // -------- PV: pool = P @ X, X staged 32 m-rows/iter -------------------
    f32x4 pool[4];
    #pragma unroll
    for (int fi = 0; fi < 4; ++fi) pool[fi] = f32x4{0.f, 0.f, 0.f, 0.f};

    #pragma unroll 1
    for (int mt2 = 0; mt2 < 16; ++mt2) {
        // A-frag (P) from S — independent of XsBuf, overlaps staging latency
        bfrag pa;
        {
            const float* sp = &S[nsub * 16 + l16][mt2 * 32 + lg * 8];
            float4 a0 = *reinterpret_cast<const float4*>(sp);
            float4 a1 = *reinterpret_cast<const float4*>(sp + 4);
            short t[8] = { f2bf(a0.x), f2bf(a0.y), f2bf(a0.z), f2bf(a0.w),
                           f2bf(a1.x), f2bf(a1.y), f2bf(a1.z), f2bf(a1.w) };
            pa = *reinterpret_cast<bfrag*>(t);
        }
        __syncthreads();               // previous X tile fully consumed
        {   // stage X tile [32 m][128 f] bf16, stride 140 shorts
            int r = tid >> 3, q = tid & 7;
            const float* src = X + ((size_t)(bt * NN + mt2 * 32 + r)) * NFG + q * 16;
            float4 v0 = reinterpret_cast<const float4*>(src)[0];
            float4 v1 = reinterpret_cast<const float4*>(src)[1];
            float4 v2 = reinterpret_cast<const float4*>(src)[2];
            float4 v3 = reinterpret_cast<const float4*>(src)[3];
            short t[16] = { f2bf(v0.x), f2bf(v0.y), f2bf(v0.z), f2bf(v0.w),
                            f2bf(v1.x), f2bf(v1.y), f2bf(v1.z), f2bf(v1.w),
                            f2bf(v2.x), f2bf(v2.y), f2bf(v2.z), f2bf(v2.w),
                            f2bf(v3.x), f2bf(v3.y), f2bf(v3.z), f2bf(v3.w) };
            short* dst = &XsBuf[r * 140 + q * 16];
            #pragma unroll
            for (int k = 0; k < 4; ++k)
                reinterpret_cast<uint2*>(dst)[k] = reinterpret_cast<uint2*>(t)[k];
        }
        __syncthreads();
        #pragma unroll
        for (int fi = 0; fi < 4; ++fi) {
            int f = (mhalf * 4 + fi) * 16 + l16;
            short t[8];
            #pragma unroll
            for (int e = 0; e < 8; ++e) t[e] = XsBuf[(lg * 8 + e) * 140 + f];
            bfrag xb = *reinterpret_cast<bfrag*>(t);
            pool[fi] = __builtin_amdgcn_mfma_f32_16x16x32_bf16(pa, xb, pool[fi], 0, 0, 0);
        }
    }
    __syncthreads();

    // -------- pool -> poolS (scaled by 1/sum), stride 136 (16B-aligned) --
    #pragma unroll
    for (int fi = 0; fi < 4; ++fi) {
        int f = (mhalf * 4 + fi) * 16 + l16;
        #pragma unroll
        for (int r = 0; r < 4; ++r) {
            int nl = nsub * 16 + lg * 4 + r;
            XsBuf[nl * 136 + f] = f2bf(pool[fi][r] * invS[nl]);
        }
    }
    __syncthreads();

    // -------- out = poolS @ W ---------------------------------------------
    bfrag a2[4];
    #pragma unroll
    for (int kk = 0; kk < 4; ++kk)
        a2[kk] = *reinterpret_cast<const bfrag*>(
            &XsBuf[(nsub * 16 + l16) * 136 + kk * 32 + lg * 8]);
    #pragma unroll
    for (int gi = 0; gi < 4; ++gi) {
        int gsub = mhalf * 4 + gi;
        f32x4 o = {0.f, 0.f, 0.f, 0.f};
        #pragma unroll
        for (int kk = 0; kk < 4; ++kk) {
            bfrag b2 = *reinterpret_cast<const bfrag*>(
                &WtB[(gsub * 16 + l16) * NFG + kk * 32 + lg * 8]);
            o = __builtin_amdgcn_mfma_f32_16x16x32_bf16(a2[kk], b2, o, 0, 0, 0);
        }
        #pragma unroll
        for (int r = 0; r < 4; ++r) {
            int n = n0 + nsub * 16 + lg * 4 + r;
            outG[((size_t)(bt * NN + n)) * NFG + gsub * 16 + l16] = o[r];
        }
    }
}

// ---------------------------------------------------------------------------
// Fallback path (proven round-4 kernels), used only if ws is too small.
__global__ __launch_bounds__(512) void k_sim(const short* __restrict__ thetaS,
                                             const short* __restrict__ phiS,
                                             const float* __restrict__ boxes,
                                             float* __restrict__ rgG) {
    __shared__ float S[64][516];
    __shared__ float cxs[NN], cys[NN];
    const int bt = blockIdx.y, n0 = blockIdx.x * 64, tid = threadIdx.x;
    const int wid = tid >> 6, lane = tid & 63;
    const int l16 = lane & 15, lg = lane >> 4;
    const int rsub = wid & 3, ch = wid >> 2;

    {
        float4 b = reinterpret_cast<const float4*>(boxes)[bt * NN + tid];
        cxs[tid] = __fmul_rn(__fadd_rn(b.x, b.z), 0.5f);
        cys[tid] = __fmul_rn(__fadd_rn(b.y, b.w), 0.5f);
    }
    bfrag thA[2];
    #pragma unroll
    for (int kk = 0; kk < 2; ++kk)
        thA[kk] = *reinterpret_cast<const bfrag*>(
            &thetaS[((size_t)(bt * NN + n0 + rsub * 16 + l16)) * NFR + kk * 32 + lg * 8]);
    __syncthreads();

    #pragma unroll 1
    for (int mt = 0; mt < 8; ++mt) {
        int m0 = mt * 64;
        #pragma unroll
        for (int ci = 0; ci < 2; ++ci) {
            int cs = ch * 2 + ci;
            int m = m0 + cs * 16 + l16;
            f32x4 acc = {0.f, 0.f, 0.f, 0.f};
            #pragma unroll
            for (int kk = 0; kk < 2; ++kk) {
                bfrag pb = *reinterpret_cast<const bfrag*>(
                    &phiS[((size_t)(bt * NN + m)) * NFR + kk * 32 + lg * 8]);
                acc = __builtin_amdgcn_mfma_f32_16x16x32_bf16(thA[kk], pb, acc, 0, 0, 0);
            }
            float cxm = cxs[m], cym = cys[m];
            #pragma unroll
            for (int r = 0; r < 4; ++r) {
                int nl = rsub * 16 + lg * 4 + r;
                float dx = __fsub_rn(cxs[n0 + nl], cxm);
                float dy = __fsub_rn(cys[n0 + nl], cym);
                float d2 = __fadd_rn(__fmul_rn(dx, dx), __fmul_rn(dy, dy));
                S[nl][m] = (d2 > __uint_as_float(0x43800001u))
                               ? -__builtin_inff() : acc[r] * 0.125f;
            }
        }
    }
    __syncthreads();
    {
        int row = tid >> 3, j = tid & 7;
        float* Sp = &S[row][j * 64];
        float mx = -__builtin_inff();
        #pragma unroll
        for (int k = 0; k < 16; ++k) {
            float4 v = *reinterpret_cast<float4*>(Sp + k * 4);
            mx = fmaxf(mx, fmaxf(fmaxf(v.x, v.y), fmaxf(v.z, v.w)));
        }
        mx = fmaxf(mx, __shfl_xor(mx, 1));
        mx = fmaxf(mx, __shfl_xor(mx, 2));
        mx = fmaxf(mx, __shfl_xor(mx, 4));
        float sm = 0.f;
        #pragma unroll
        for (int k = 0; k < 16; ++k) {
            float4 v = *reinterpret_cast<float4*>(Sp + k * 4);
            v.x = __expf(v.x - mx); v.y = __expf(v.y - mx);
            v.z = __expf(v.z - mx); v.w = __expf(v.w - mx);
            sm += (v.x + v.y) + (v.z + v.w);
            *reinterpret_cast<float4*>(Sp + k * 4) = v;
        }
        sm += __shfl_xor(sm, 1);
        sm += __shfl_xor(sm, 2);
        sm += __shfl_xor(sm, 4);
        float inv = 1.0f / sm;
        float* rp = rgG + ((size_t)(bt * NN) + n0 + row) * NN + j * 64;
        #pragma unroll
        for (int k = 0; k < 16; ++k) {
            float4 a = *reinterpret_cast<float4*>(Sp + k * 4);
            a.x *= inv; a.y *= inv; a.z *= inv; a.w *= inv;
            *reinterpret_cast<float4*>(rp + k * 4) = a;
        }
    }
}

__global__ __launch_bounds__(256) void k_pool(const float* __restrict__ rgG,
                                              const float* __restrict__ X,
                                              const float* __restrict__ W,
                                              float* __restrict__ outG) {
    __shared__ short Xt[128][72];
    __shared__ short poolS[64][136];
    __shared__ short WtS[128][136];
    const int bt = blockIdx.y, n0 = blockIdx.x * 64, tid = threadIdx.x;
    const int wid = tid >> 6, lane = tid & 63;
    const int l16 = lane & 15, lg = lane >> 4;

    #pragma unroll
    for (int k = 0; k < 64; ++k) {
        int idx = k * 256 + tid;
        int f = idx >> 7, g = idx & 127;
        WtS[g][f] = f2bf(W[idx]);
    }
    f32x4 acc[8];
    #pragma unroll
    for (int ft = 0; ft < 8; ++ft) acc[ft] = f32x4{0.f, 0.f, 0.f, 0.f};

    #pragma unroll 1
    for (int mt = 0; mt < 8; ++mt) {
        __syncthreads();
        {
            int m = tid >> 2, seg = tid & 3;
            const float* src = X + ((size_t)(bt * NN + mt * 64 + m)) * NFG + seg * 32;
            #pragma unroll
            for (int k = 0; k < 8; ++k) {
                float4 v = reinterpret_cast<const float4*>(src)[k];
                int f = seg * 32 + k * 4;
                Xt[f + 0][m] = f2bf(v.x); Xt[f + 1][m] = f2bf(v.y);
                Xt[f + 2][m] = f2bf(v.z); Xt[f + 3][m] = f2bf(v.w);
            }
        }
        bfrag pa[2];
        const float* prow = rgG + ((size_t)(bt * NN + n0 + wid * 16 + l16)) * NN + mt * 64;
        #pragma unroll
        for (int kk = 0; kk < 2; ++kk) {
            float4 a = *reinterpret_cast<const float4*>(prow + kk * 32 + lg * 8);
            float4 b = *reinterpret_cast<const float4*>(prow + kk * 32 + lg * 8 + 4);
            short t[8] = { f2bf(a.x), f2bf(a.y), f2bf(a.z), f2bf(a.w),
                           f2bf(b.x), f2bf(b.y), f2bf(b.z), f2bf(b.w) };
            pa[kk] = *reinterpret_cast<bfrag*>(t);
        }
        __syncthreads();
        #pragma unroll
        for (int ft = 0; ft < 8; ++ft) {
            #pragma unroll
            for (int kk = 0; kk < 2; ++kk) {
                bfrag b = *reinterpret_cast<const bfrag*>(
                    &Xt[ft * 16 + l16][kk * 32 + lg * 8]);
                acc[ft] = __builtin_amdgcn_mfma_f32_16x16x32_bf16(pa[kk], b, acc[ft], 0, 0, 0);
            }
        }
    }
    __syncthreads();
    #pragma unroll
    for (int ft = 0; ft < 8; ++ft)
        #pragma unroll
        for (int r = 0; r < 4; ++r)
            poolS[wid * 16 + lg * 4 + r][ft * 16 + l16] = f2bf(acc[ft][r]);
    __syncthreads();

    bfrag a2[4];
    #pragma unroll
    for (int kk = 0; kk < 4; ++kk)
        a2[kk] = *reinterpret_cast<const bfrag*>(&poolS[wid * 16 + l16][kk * 32 + lg * 8]);
    #pragma unroll
    for (int gt = 0; gt < 8; ++gt) {
        f32x4 o = {0.f, 0.f, 0.f, 0.f};
        #pragma unroll
        for (int kk = 0; kk < 4; ++kk) {
            bfrag b2 = *reinterpret_cast<const bfrag*>(&WtS[gt * 16 + l16][kk * 32 + lg * 8]);
            o = __builtin_amdgcn_mfma_f32_16x16x32_bf16(a2[kk], b2, o, 0, 0, 0);
        }
        #pragma unroll
        for (int r = 0; r < 4; ++r) {
            int n = n0 + wid * 16 + lg * 4 + r;
            outG[((size_t)(bt * NN + n)) * NFG + gt * 16 + l16] = o[r];
        }
    }
}

// ---------------------------------------------------------------------------
extern "C" void kernel_launch(void* const* d_in, const int* in_sizes, int n_in,
                              void* d_out, int out_size, void* d_ws, size_t ws_size,
                              hipStream_t stream) {
    const float* X     = (const float*)d_in[0];
    const float* boxes = (const float*)d_in[1];
    const float* W     = (const float*)d_in[2];
    const float* thw   = (const float*)d_in[3];
    const float* thb   = (const float*)d_in[4];
    const float* phw   = (const float*)d_in[5];
    const float* phb   = (const float*)d_in[6];

    float* outR = (float*)d_out;                       // [256*512][128] f32
    float* rgR  = outR + (size_t)BT * NN * NFG;        // [256*512][512] f32

    const size_t WS_NEED = (size_t)BT * NN * NFR * 2 * 2 + (size_t)NFG * NFG * 2;
    if (ws_size >= WS_NEED) {
        // fused path: theta/phi/WtB in workspace
        short* thetaS = (short*)d_ws;                       // 16,777,216 B
        short* phiS   = thetaS + (size_t)BT * NN * NFR;     // 16,777,216 B
        short* WtB    = phiS + (size_t)BT * NN * NFR;       //     32,768 B
        k_prep <<<64, 256, 0, stream>>>(W, WtB);
        k_proj <<<dim3(8, BT), 256, 0, stream>>>(X, thw, thb, phw, phb, thetaS, phiS);
        k_fused<<<4096, 256, 0, stream>>>(thetaS, phiS, WtB, X, boxes, outR, rgR);
    } else {
        // proven round-4 path: theta/phi scratch inside the out region
        short* thetaS = (short*)d_out;
        short* phiS   = thetaS + (size_t)BT * NN * NFR;
        k_proj<<<dim3(8, BT), 256, 0, stream>>>(X, thw, thb, phw, phb, thetaS, phiS);
        k_sim <<<dim3(8, BT), 512, 0, stream>>>(thetaS, phiS, boxes, rgR);
        k_pool<<<dim3(8, BT), 256, 0, stream>>>(rgR, X, W, outR);
    }
}

// Round 6
// 250.303 us; speedup vs baseline: 1.4671x; 1.1665x over previous
//
#include <hip/hip_runtime.h>
#include <hip/hip_bf16.h>

#define NN 512
#define NFG 128
#define NFR 64
#define BT 256

typedef __attribute__((ext_vector_type(8))) short bfrag;   // 8 bf16
typedef __attribute__((ext_vector_type(4))) float f32x4;

__device__ __forceinline__ short f2bf(float f) {
    unsigned u = __float_as_uint(f);
    return (short)((u + 0x7fffu + ((u >> 16) & 1u)) >> 16);
}
__device__ __forceinline__ float bf2f(short s) {
    return __uint_as_float(((unsigned)(unsigned short)s) << 16);
}

// ---------------------------------------------------------------------------
// k_prep: WtB[g][f] = bf16(W[f][g])
__global__ __launch_bounds__(256) void k_prep(const float* __restrict__ W,
                                              short* __restrict__ WtB) {
    int i = blockIdx.x * 256 + threadIdx.x;
    if (i < NFG * NFG) { int f = i >> 7, g = i & 127; WtB[g * NFG + f] = f2bf(W[i]); }
}

// ---------------------------------------------------------------------------
// k_projF: theta = X@thw^T + thb ; phi = X@phw^T + phb ; Yt = (X@W)^T
// theta/phi: [BT*512][64] bf16 ; Yt: [BT*128 g][512 m] bf16 (row-major in g)
__global__ __launch_bounds__(256) void k_projF(const float* __restrict__ X,
                                               const float* __restrict__ thw,
                                               const float* __restrict__ thb,
                                               const float* __restrict__ phw,
                                               const float* __restrict__ phb,
                                               const short* __restrict__ WtB,
                                               short* __restrict__ thetaS,
                                               short* __restrict__ phiS,
                                               short* __restrict__ YtG) {
    __shared__ short Xs[64][136];
    __shared__ short wS[2][64][136];
    __shared__ float bS[2][64];
    const int bt = blockIdx.y, n0 = blockIdx.x * 64, tid = threadIdx.x;

    {   // stage X tile (f32 -> bf16)
        int row = tid >> 2, seg = tid & 3;
        const float* src = X + ((size_t)(bt * NN + n0 + row)) * NFG + seg * 32;
        short tmp[32];
        #pragma unroll
        for (int k = 0; k < 8; ++k) {
            float4 v = reinterpret_cast<const float4*>(src)[k];
            tmp[k*4+0] = f2bf(v.x); tmp[k*4+1] = f2bf(v.y);
            tmp[k*4+2] = f2bf(v.z); tmp[k*4+3] = f2bf(v.w);
        }
        #pragma unroll
        for (int k = 0; k < 4; ++k)
            reinterpret_cast<uint4*>(&Xs[row][seg * 32])[k] =
                reinterpret_cast<uint4*>(tmp)[k];
    }
    #pragma unroll
    for (int k = 0; k < 32; ++k) {
        int idx = k * 256 + tid;
        int r = idx >> 7, f = idx & 127;
        wS[0][r][f] = f2bf(thw[idx]);
        wS[1][r][f] = f2bf(phw[idx]);
    }
    if (tid < 64) { bS[0][tid] = thb[tid]; bS[1][tid] = phb[tid]; }
    __syncthreads();

    const int wid = tid >> 6, lane = tid & 63;
    const int l16 = lane & 15, lg = lane >> 4;

    bfrag xa[4];
    #pragma unroll
    for (int kk = 0; kk < 4; ++kk)
        xa[kk] = *reinterpret_cast<const bfrag*>(&Xs[wid * 16 + l16][kk * 32 + lg * 8]);

    for (int pass = 0; pass < 2; ++pass) {
        short* dst = pass ? phiS : thetaS;
        #pragma unroll
        for (int c = 0; c < 4; ++c) {
            f32x4 acc = {0.f, 0.f, 0.f, 0.f};
            #pragma unroll
            for (int kk = 0; kk < 4; ++kk) {
                bfrag b = *reinterpret_cast<const bfrag*>(
                    &wS[pass][c * 16 + l16][kk * 32 + lg * 8]);
                acc = __builtin_amdgcn_mfma_f32_16x16x32_bf16(xa[kk], b, acc, 0, 0, 0);
            }
            float bv = bS[pass][c * 16 + l16];
            #pragma unroll
            for (int r = 0; r < 4; ++r) {
                int n = n0 + wid * 16 + lg * 4 + r;
                dst[((size_t)(bt * NN + n)) * NFR + c * 16 + l16] = f2bf(acc[r] + bv);
            }
        }
    }

    // Yt[g][m] = sum_f Wt[g][f] * X[m][f]   (A = WtB rows g, B = Xs cols m)
    #pragma unroll
    for (int gi = 0; gi < 2; ++gi) {
        int gs = wid * 2 + gi;
        bfrag wa[4];
        #pragma unroll
        for (int kk = 0; kk < 4; ++kk)
            wa[kk] = *reinterpret_cast<const bfrag*>(
                &WtB[(gs * 16 + l16) * NFG + kk * 32 + lg * 8]);
        #pragma unroll
        for (int ms = 0; ms < 4; ++ms) {
            f32x4 acc = {0.f, 0.f, 0.f, 0.f};
            #pragma unroll
            for (int kk = 0; kk < 4; ++kk) {
                bfrag xb = *reinterpret_cast<const bfrag*>(
                    &Xs[ms * 16 + l16][kk * 32 + lg * 8]);
                acc = __builtin_amdgcn_mfma_f32_16x16x32_bf16(wa[kk], xb, acc, 0, 0, 0);
            }
            #pragma unroll
            for (int r = 0; r < 4; ++r) {
                int g = gs * 16 + lg * 4 + r;
                int m = n0 + ms * 16 + l16;
                YtG[((size_t)(bt * NFG + g)) * NN + m] = f2bf(acc[r]);
            }
        }
    }
}

// ---------------------------------------------------------------------------
// k_fused: per (frame, 32-n block):
//   QK^T (sim^T orientation: A=phi, B=theta) + exact mask -> bf16 S
//   -> softmax (16 lanes/row, conflict-free, rg f32 from regs)
//   -> PV: out = exp(S) @ Yt, ZERO barriers, B-frags straight from global Yt
__global__ __launch_bounds__(256, 4) void k_fused(const short* __restrict__ thetaS,
                                                  const short* __restrict__ phiS,
                                                  const short* __restrict__ YtG,
                                                  const float* __restrict__ boxes,
                                                  float* __restrict__ outG,
                                                  float* __restrict__ rgG) {
    __shared__ short S[32][520];          // 33,280 B (exp, bf16; stride 520 -> 2-way max)
    __shared__ float cxs[NN], cys[NN];    //  4,096 B
    __shared__ float invS[32];            //    128 B
    // total 37.5 KB -> 4 blocks/CU

    // XCD swizzle: 16 blocks of one frame land consecutively on one XCD
    const int bid = blockIdx.x;                    // 0..4095
    const int jj = bid >> 3;
    const int bt = (bid & 7) * 32 + (jj >> 4);
    const int n0 = (jj & 15) * 32;
    const int tid = threadIdx.x;
    const int wid = tid >> 6, lane = tid & 63;
    const int l16 = lane & 15, lg = lane >> 4;

    {   // centers: bit-exact vs numpy f32 RNE
        float4 b0 = reinterpret_cast<const float4*>(boxes)[bt * NN + tid];
        float4 b1 = reinterpret_cast<const float4*>(boxes)[bt * NN + 256 + tid];
        cxs[tid]       = __fmul_rn(__fadd_rn(b0.x, b0.z), 0.5f);
        cys[tid]       = __fmul_rn(__fadd_rn(b0.y, b0.w), 0.5f);
        cxs[256 + tid] = __fmul_rn(__fadd_rn(b1.x, b1.z), 0.5f);
        cys[256 + tid] = __fmul_rn(__fadd_rn(b1.y, b1.w), 0.5f);
    }

    // B-fragments: theta of this block's 32 rows (col = n)
    const int nsub2 = wid & 1, mq = wid >> 1;
    bfrag thB[2];
    #pragma unroll
    for (int kk = 0; kk < 2; ++kk)
        thB[kk] = *reinterpret_cast<const bfrag*>(
            &thetaS[((size_t)(bt * NN + n0 + nsub2 * 16 + l16)) * NFR + kk * 32 + lg * 8]);
    __syncthreads();

    // -------- QK: sim^T -> masked bf16 into S[n][m] ----------------------
    const int nloc = nsub2 * 16 + l16;
    const float cxn = cxs[n0 + nloc], cyn = cys[n0 + nloc];
    #pragma unroll 4
    for (int i = 0; i < 16; ++i) {
        const int m_base = mq * 256 + i * 16;
        const short* prow = &phiS[((size_t)(bt * NN + m_base + l16)) * NFR + lg * 8];
        bfrag pa0 = *reinterpret_cast<const bfrag*>(prow);
        bfrag pa1 = *reinterpret_cast<const bfrag*>(prow + 32);
        f32x4 acc = {0.f, 0.f, 0.f, 0.f};
        acc = __builtin_amdgcn_mfma_f32_16x16x32_bf16(pa0, thB[0], acc, 0, 0, 0);
        acc = __builtin_amdgcn_mfma_f32_16x16x32_bf16(pa1, thB[1], acc, 0, 0, 0);
        #pragma unroll
        for (int r = 0; r < 4; ++r) {
            int m = m_base + lg * 4 + r;
            // masked <=> sqrt_RNE(d2) > 16.0f <=> d2 > 256+2^-15
            float dx = __fsub_rn(cxn, cxs[m]);
            float dy = __fsub_rn(cyn, cys[m]);
            float d2 = __fadd_rn(__fmul_rn(dx, dx), __fmul_rn(dy, dy));
            float v = (d2 > __uint_as_float(0x43800001u))
                          ? -__builtin_inff() : acc[r] * 0.125f;
            S[nloc][m] = f2bf(v);
        }
    }
    __syncthreads();

    // -------- softmax: 16 lanes per row-slice, all accesses 256B-contig --
    {
        const int g16 = tid >> 4, li = tid & 15;
        #pragma unroll
        for (int rr = 0; rr < 2; ++rr) {
            const int row = g16 * 2 + rr;
            short* sp = &S[row][0];
            float f[32];
            #pragma unroll
            for (int k = 0; k < 4; ++k) {
                bfrag c = *reinterpret_cast<bfrag*>(sp + (li + 16 * k) * 8);
                #pragma unroll
                for (int e = 0; e < 8; ++e) f[k * 8 + e] = bf2f(c[e]);
            }
            float mx = f[0];
            #pragma unroll
            for (int j = 1; j < 32; ++j) mx = fmaxf(mx, f[j]);
            mx = fmaxf(mx, __shfl_xor(mx, 1));
            mx = fmaxf(mx, __shfl_xor(mx, 2));
            mx = fmaxf(mx, __shfl_xor(mx, 4));
            mx = fmaxf(mx, __shfl_xor(mx, 8));
            float sm = 0.f;
            #pragma unroll
            for (int j = 0; j < 32; ++j) { f[j] = __expf(f[j] - mx); sm += f[j]; }
            sm += __shfl_xor(sm, 1);
            sm += __shfl_xor(sm, 2);
            sm += __shfl_xor(sm, 4);
            sm += __shfl_xor(sm, 8);
            float inv = 1.0f / sm;
            if (li == 0) invS[row] = inv;
            float* rp = rgG + ((size_t)(bt * NN) + n0 + row) * NN;
            #pragma unroll
            for (int k = 0; k < 4; ++k) {
                int c0 = (li + 16 * k) * 8;
                float4 a = {f[k*8+0]*inv, f[k*8+1]*inv, f[k*8+2]*inv, f[k*8+3]*inv};
                float4 b = {f[k*8+4]*inv, f[k*8+5]*inv, f[k*8+6]*inv, f[k*8+7]*inv};
                *reinterpret_cast<float4*>(rp + c0)     = a;
                *reinterpret_cast<float4*>(rp + c0 + 4) = b;
                short t[8] = { f2bf(f[k*8+0]), f2bf(f[k*8+1]), f2bf(f[k*8+2]), f2bf(f[k*8+3]),
                               f2bf(f[k*8+4]), f2bf(f[k*8+5]), f2bf(f[k*8+6]), f2bf(f[k*8+7]) };
                *reinterpret_cast<bfrag*>(sp + c0) = *reinterpret_cast<bfrag*>(t);
            }
        }
    }
    __syncthreads();

    // -------- PV: out = exp(S) @ Yt  (no barriers, no LDS staging) -------
    const int nsub = wid & 1, gq = wid >> 1;
    f32x4 pool[4];
    #pragma unroll
    for (int gi = 0; gi < 4; ++gi) pool[gi] = f32x4{0.f, 0.f, 0.f, 0.f};

    #pragma unroll 4
    for (int mt2 = 0; mt2 < 16; ++mt2) {
        bfrag pa = *reinterpret_cast<const bfrag*>(&S[nsub * 16 + l16][mt2 * 32 + lg * 8]);
        #pragma unroll
        for (int gi = 0; gi < 4; ++gi) {
            int g = gq * 64 + gi * 16 + l16;
            bfrag yb = *reinterpret_cast<const bfrag*>(
                &YtG[((size_t)(bt * NFG + g)) * NN + mt2 * 32 + lg * 8]);
            pool[gi] = __builtin_amdgcn_mfma_f32_16x16x32_bf16(pa, yb, pool[gi], 0, 0, 0);
        }
    }
    #pragma unroll
    for (int gi = 0; gi < 4; ++gi) {
        #pragma unroll
        for (int r = 0; r < 4; ++r) {
            int nl = nsub * 16 + lg * 4 + r;
            outG[((size_t)(bt * NN + n0 + nl)) * NFG + gq * 64 + gi * 16 + l16]
                = pool[gi][r] * invS[nl];
        }
    }
}

// ---------------------------------------------------------------------------
// Fallback path (proven round-4 kernels), used only if ws is too small.
__global__ __launch_bounds__(256) void k_proj(const float* __restrict__ X,
                                              const float* __restrict__ thw,
                                              const float* __restrict__ thb,
                                              const float* __restrict__ phw,
                                              const float* __restrict__ phb,
                                              short* __restrict__ thetaS,
                                              short* __restrict__ phiS) {
    __shared__ short Xs[64][136];
    __shared__ short wS[2][64][136];
    __shared__ float bS[2][64];
    const int bt = blockIdx.y, n0 = blockIdx.x * 64, tid = threadIdx.x;
    {
        int row = tid >> 2, seg = tid & 3;
        const float* src = X + ((size_t)(bt * NN + n0 + row)) * NFG + seg * 32;
        short tmp[32];
        #pragma unroll
        for (int k = 0; k < 8; ++k) {
            float4 v = reinterpret_cast<const float4*>(src)[k];
            tmp[k*4+0] = f2bf(v.x); tmp[k*4+1] = f2bf(v.y);
            tmp[k*4+2] = f2bf(v.z); tmp[k*4+3] = f2bf(v.w);
        }
        #pragma unroll
        for (int k = 0; k < 4; ++k)
            reinterpret_cast<uint4*>(&Xs[row][seg * 32])[k] =
                reinterpret_cast<uint4*>(tmp)[k];
    }
    #pragma unroll
    for (int k = 0; k < 32; ++k) {
        int idx = k * 256 + tid;
        int r = idx >> 7, f = idx & 127;
        wS[0][r][f] = f2bf(thw[idx]);
        wS[1][r][f] = f2bf(phw[idx]);
    }
    if (tid < 64) { bS[0][tid] = thb[tid]; bS[1][tid] = phb[tid]; }
    __syncthreads();
    const int wid = tid >> 6, lane = tid & 63;
    const int l16 = lane & 15, lg = lane >> 4;
    bfrag xa[4];
    #pragma unroll
    for (int kk = 0; kk < 4; ++kk)
        xa[kk] = *reinterpret_cast<const bfrag*>(&Xs[wid * 16 + l16][kk * 32 + lg * 8]);
    for (int pass = 0; pass < 2; ++pass) {
        short* dst = pass ? phiS : thetaS;
        #pragma unroll
        for (int c = 0; c < 4; ++c) {
            f32x4 acc = {0.f, 0.f, 0.f, 0.f};
            #pragma unroll
            for (int kk = 0; kk < 4; ++kk) {
                bfrag b = *reinterpret_cast<const bfrag*>(
                    &wS[pass][c * 16 + l16][kk * 32 + lg * 8]);
                acc = __builtin_amdgcn_mfma_f32_16x16x32_bf16(xa[kk], b, acc, 0, 0, 0);
            }
            float bv = bS[pass][c * 16 + l16];
            #pragma unroll
            for (int r = 0; r < 4; ++r) {
                int n = n0 + wid * 16 + lg * 4 + r;
                dst[((size_t)(bt * NN + n)) * NFR + c * 16 + l16] = f2bf(acc[r] + bv);
            }
        }
    }
}

__global__ __launch_bounds__(512) void k_sim(const short* __restrict__ thetaS,
                                             const short* __restrict__ phiS,
                                             const float* __restrict__ boxes,
                                             float* __restrict__ rgG) {
    __shared__ float S[64][516];
    __shared__ float cxs[NN], cys[NN];
    const int bt = blockIdx.y, n0 = blockIdx.x * 64, tid = threadIdx.x;
    const int wid = tid >> 6, lane = tid & 63;
    const int l16 = lane & 15, lg = lane >> 4;
    const int rsub = wid & 3, ch = wid >> 2;
    {
        float4 b = reinterpret_cast<const float4*>(boxes)[bt * NN + tid];
        cxs[tid] = __fmul_rn(__fadd_rn(b.x, b.z), 0.5f);
        cys[tid] = __fmul_rn(__fadd_rn(b.y, b.w), 0.5f);
    }
    bfrag thA[2];
    #pragma unroll
    for (int kk = 0; kk < 2; ++kk)
        thA[kk] = *reinterpret_cast<const bfrag*>(
            &thetaS[((size_t)(bt * NN + n0 + rsub * 16 + l16)) * NFR + kk * 32 + lg * 8]);
    __syncthreads();
    #pragma unroll 1
    for (int mt = 0; mt < 8; ++mt) {
        int m0 = mt * 64;
        #pragma unroll
        for (int ci = 0; ci < 2; ++ci) {
            int cs = ch * 2 + ci;
            int m = m0 + cs * 16 + l16;
            f32x4 acc = {0.f, 0.f, 0.f, 0.f};
            #pragma unroll
            for (int kk = 0; kk < 2; ++kk) {
                bfrag pb = *reinterpret_cast<const bfrag*>(
                    &phiS[((size_t)(bt * NN + m)) * NFR + kk * 32 + lg * 8]);
                acc = __builtin_amdgcn_mfma_f32_16x16x32_bf16(thA[kk], pb, acc, 0, 0, 0);
            }
            float cxm = cxs[m], cym = cys[m];
            #pragma unroll
            for (int r = 0; r < 4; ++r) {
                int nl = rsub * 16 + lg * 4 + r;
                float dx = __fsub_rn(cxs[n0 + nl], cxm);
                float dy = __fsub_rn(cys[n0 + nl], cym);
                float d2 = __fadd_rn(__fmul_rn(dx, dx), __fmul_rn(dy, dy));
                S[nl][m] = (d2 > __uint_as_float(0x43800001u))
                               ? -__builtin_inff() : acc[r] * 0.125f;
            }
        }
    }
    __syncthreads();
    {
        int row = tid >> 3, j = tid & 7;
        float* Sp = &S[row][j * 64];
        float mx = -__builtin_inff();
        #pragma unroll
        for (int k = 0; k < 16; ++k) {
            float4 v = *reinterpret_cast<float4*>(Sp + k * 4);
            mx = fmaxf(mx, fmaxf(fmaxf(v.x, v.y), fmaxf(v.z, v.w)));
        }
        mx = fmaxf(mx, __shfl_xor(mx, 1));
        mx = fmaxf(mx, __shfl_xor(mx, 2));
        mx = fmaxf(mx, __shfl_xor(mx, 4));
        float sm = 0.f;
        #pragma unroll
        for (int k = 0; k < 16; ++k) {
            float4 v = *reinterpret_cast<float4*>(Sp + k * 4);
            v.x = __expf(v.x - mx); v.y = __expf(v.y - mx);
            v.z = __expf(v.z - mx); v.w = __expf(v.w - mx);
            sm += (v.x + v.y) + (v.z + v.w);
            *reinterpret_cast<float4*>(Sp + k * 4) = v;
        }
        sm += __shfl_xor(sm, 1);
        sm += __shfl_xor(sm, 2);
        sm += __shfl_xor(sm, 4);
        float inv = 1.0f / sm;
        float* rp = rgG + ((size_t)(bt * NN) + n0 + row) * NN + j * 64;
        #pragma unroll
        for (int k = 0; k < 16; ++k) {
            float4 a = *reinterpret_cast<float4*>(Sp + k * 4);
            a.x *= inv; a.y *= inv; a.z *= inv; a.w *= inv;
            *reinterpret_cast<float4*>(rp + k * 4) = a;
        }
    }
}

__global__ __launch_bounds__(256) void k_pool(const float* __restrict__ rgG,
                                              const float* __restrict__ X,
                                              const float* __restrict__ W,
                                              float* __restrict__ outG) {
    __shared__ short Xt[128][72];
    __shared__ short poolS[64][136];
    __shared__ short WtS[128][136];
    const int bt = blockIdx.y, n0 = blockIdx.x * 64, tid = threadIdx.x;
    const int wid = tid >> 6, lane = tid & 63;
    const int l16 = lane & 15, lg = lane >> 4;
    #pragma unroll
    for (int k = 0; k < 64; ++k) {
        int idx = k * 256 + tid;
        int f = idx >> 7, g = idx & 127;
        WtS[g][f] = f2bf(W[idx]);
    }
    f32x4 acc[8];
    #pragma unroll
    for (int ft = 0; ft < 8; ++ft) acc[ft] = f32x4{0.f, 0.f, 0.f, 0.f};
    #pragma unroll 1
    for (int mt = 0; mt < 8; ++mt) {
        __syncthreads();
        {
            int m = tid >> 2, seg = tid & 3;
            const float* src = X + ((size_t)(bt * NN + mt * 64 + m)) * NFG + seg * 32;
            #pragma unroll
            for (int k = 0; k < 8; ++k) {
                float4 v = reinterpret_cast<const float4*>(src)[k];
                int f = seg * 32 + k * 4;
                Xt[f + 0][m] = f2bf(v.x); Xt[f + 1][m] = f2bf(v.y);
                Xt[f + 2][m] = f2bf(v.z); Xt[f + 3][m] = f2bf(v.w);
            }
        }
        bfrag pa[2];
        const float* prow = rgG + ((size_t)(bt * NN + n0 + wid * 16 + l16)) * NN + mt * 64;
        #pragma unroll
        for (int kk = 0; kk < 2; ++kk) {
            float4 a = *reinterpret_cast<const float4*>(prow + kk * 32 + lg * 8);
            float4 b = *reinterpret_cast<const float4*>(prow + kk * 32 + lg * 8 + 4);
            short t[8] = { f2bf(a.x), f2bf(a.y), f2bf(a.z), f2bf(a.w),
                           f2bf(b.x), f2bf(b.y), f2bf(b.z), f2bf(b.w) };
            pa[kk] = *reinterpret_cast<bfrag*>(t);
        }
        __syncthreads();
        #pragma unroll
        for (int ft = 0; ft < 8; ++ft) {
            #pragma unroll
            for (int kk = 0; kk < 2; ++kk) {
                bfrag b = *reinterpret_cast<const bfrag*>(
                    &Xt[ft * 16 + l16][kk * 32 + lg * 8]);
                acc[ft] = __builtin_amdgcn_mfma_f32_16x16x32_bf16(pa[kk], b, acc[ft], 0, 0, 0);
            }
        }
    }
    __syncthreads();
    #pragma unroll
    for (int ft = 0; ft < 8; ++ft)
        #pragma unroll
        for (int r = 0; r < 4; ++r)
            poolS[wid * 16 + lg * 4 + r][ft * 16 + l16] = f2bf(acc[ft][r]);
    __syncthreads();
    bfrag a2[4];
    #pragma unroll
    for (int kk = 0; kk < 4; ++kk)
        a2[kk] = *reinterpret_cast<const bfrag*>(&poolS[wid * 16 + l16][kk * 32 + lg * 8]);
    #pragma unroll
    for (int gt = 0; gt < 8; ++gt) {
        f32x4 o = {0.f, 0.f, 0.f, 0.f};
        #pragma unroll
        for (int kk = 0; kk < 4; ++kk) {
            bfrag b2 = *reinterpret_cast<const bfrag*>(&WtS[gt * 16 + l16][kk * 32 + lg * 8]);
            o = __builtin_amdgcn_mfma_f32_16x16x32_bf16(a2[kk], b2, o, 0, 0, 0);
        }
        #pragma unroll
        for (int r = 0; r < 4; ++r) {
            int n = n0 + wid * 16 + lg * 4 + r;
            outG[((size_t)(bt * NN + n)) * NFG + gt * 16 + l16] = o[r];
        }
    }
}

// ---------------------------------------------------------------------------
extern "C" void kernel_launch(void* const* d_in, const int* in_sizes, int n_in,
                              void* d_out, int out_size, void* d_ws, size_t ws_size,
                              hipStream_t stream) {
    const float* X     = (const float*)d_in[0];
    const float* boxes = (const float*)d_in[1];
    const float* W     = (const float*)d_in[2];
    const float* thw   = (const float*)d_in[3];
    const float* thb   = (const float*)d_in[4];
    const float* phw   = (const float*)d_in[5];
    const float* phb   = (const float*)d_in[6];

    float* outR = (float*)d_out;                       // [256*512][128] f32
    float* rgR  = outR + (size_t)BT * NN * NFG;        // [256*512][512] f32

    const size_t TH = (size_t)BT * NN * NFR * 2;       // 16,777,216 B
    const size_t YT = (size_t)BT * NFG * NN * 2;       // 33,554,432 B
    const size_t WS_NEED = TH * 2 + YT + (size_t)NFG * NFG * 2;   // 67,141,632 B
    if (ws_size >= WS_NEED) {
        char* ws = (char*)d_ws;
        short* thetaS = (short*)(ws);
        short* phiS   = (short*)(ws + TH);
        short* YtG    = (short*)(ws + 2 * TH);
        short* WtB    = (short*)(ws + 2 * TH + YT);
        k_prep <<<64, 256, 0, stream>>>(W, WtB);
        k_projF<<<dim3(8, BT), 256, 0, stream>>>(X, thw, thb, phw, phb, WtB,
                                                 thetaS, phiS, YtG);
        k_fused<<<4096, 256, 0, stream>>>(thetaS, phiS, YtG, boxes, outR, rgR);
    } else {
        // proven round-4 path: theta/phi scratch inside the out region
        short* thetaS = (short*)d_out;
        short* phiS   = thetaS + (size_t)BT * NN * NFR;
        k_proj<<<dim3(8, BT), 256, 0, stream>>>(X, thw, thb, phw, phb, thetaS, phiS);
        k_sim <<<dim3(8, BT), 512, 0, stream>>>(thetaS, phiS, boxes, rgR);
        k_pool<<<dim3(8, BT), 256, 0, stream>>>(rgR, X, W, outR);
    }
}